// Round 4
// baseline (323.678 us; speedup 1.0000x reference)
//
#include <hip/hip_runtime.h>

#define NRES 384
#define CD   128
#define MTOT (NRES*NRES)   /* 147456 */

typedef unsigned short u16;
typedef __bf16 bf16x8 __attribute__((ext_vector_type(8)));
typedef float  f32x16 __attribute__((ext_vector_type(16)));

static __device__ __forceinline__ u16 f2bf(float f) {
  __bf16 b = (__bf16)f;
  return __builtin_bit_cast(u16, b);
}
static __device__ __forceinline__ float bf2f(u16 v) {
  return __uint_as_float(((unsigned)v) << 16);
}
static __device__ __forceinline__ float sigmoidf(float x) {
  return 1.0f / (1.0f + __expf(-x));
}

// async global->LDS, 16B per lane; LDS dest = wave-uniform base + lane*16
static __device__ __forceinline__ void gl16(const void* g, void* l) {
  __builtin_amdgcn_global_load_lds(
      (const __attribute__((address_space(1))) void*)g,
      (__attribute__((address_space(3))) void*)l, 16, 0, 0);
}

// ---------------------------------------------------------------------------
// K0: convert the six 128x128 fp32 weight matrices to bf16 (row-major [n][k])
// order in wb: a_g_w, a_p_w, b_g_w, b_p_w, g_w, z_w
// ---------------------------------------------------------------------------
__global__ void k_cvt_w(const float* w0, const float* w1, const float* w2,
                        const float* w3, const float* w4, const float* w5,
                        u16* wb) {
  int i = blockIdx.x * 256 + threadIdx.x;
  const float* srcs[6] = {w0, w1, w2, w3, w4, w5};
  wb[i] = f2bf(srcs[i >> 14][i & 16383]);
}

// ---------------------------------------------------------------------------
// K1 (fused LN + projections): per 128-row m-tile:
//  phase 1: LayerNorm(z) -> znt LDS tile (bf16, 136-padded = conflict-free)
//  phase 2: three type passes reusing the tile:
//    types 0/1 (a,b): swapped-operand MFMA -> C[h][m], coalesced [h][m] store
//    type 2 (gate):   natural order -> gate[m][o]
// ---------------------------------------------------------------------------
__global__ __launch_bounds__(256) void k_fused(
    const float* __restrict__ z, const float* __restrict__ mask,
    const float* __restrict__ lnw, const float* __restrict__ lnb,
    const u16* __restrict__ wb,
    const float* __restrict__ agb, const float* __restrict__ apb,
    const float* __restrict__ bgb, const float* __restrict__ bpb,
    const float* __restrict__ gb,
    u16* __restrict__ a_out, u16* __restrict__ b_out, u16* __restrict__ gate_out) {
  int m0 = blockIdx.x * 128;
  int lane = threadIdx.x & 63;
  int wvu = __builtin_amdgcn_readfirstlane(threadIdx.x >> 6);
  int nl = lane & 31, s = lane >> 5;
  int h = wvu * 32 + nl;

  __shared__ u16 znt[128][136];   // 34.8 KB, padded rows (272 B) = conflict-free

  // ---- phase 1: LN. Wave handles 2 rows/pass (lanes 0-31 row r, 32-63 r+1).
  {
    float4 w4 = ((const float4*)lnw)[nl];
    float4 b4 = ((const float4*)lnb)[nl];
#pragma unroll 4
    for (int p = 0; p < 16; ++p) {
      int row = wvu * 32 + p * 2 + s;
      float4 v = ((const float4*)(z + (size_t)(m0 + row) * CD))[nl];
      float sum = v.x + v.y + v.z + v.w;
#pragma unroll
      for (int off = 16; off >= 1; off >>= 1) sum += __shfl_xor(sum, off);
      float mu = sum * (1.0f / CD);
      float d0 = v.x - mu, d1 = v.y - mu, d2 = v.z - mu, d3 = v.w - mu;
      float vr = d0 * d0 + d1 * d1 + d2 * d2 + d3 * d3;
#pragma unroll
      for (int off = 16; off >= 1; off >>= 1) vr += __shfl_xor(vr, off);
      float rs = rsqrtf(vr * (1.0f / CD) + 1e-5f);
      ushort4 o;
      o.x = f2bf(d0 * rs * w4.x + b4.x);
      o.y = f2bf(d1 * rs * w4.y + b4.y);
      o.z = f2bf(d2 * rs * w4.z + b4.z);
      o.w = f2bf(d3 * rs * w4.w + b4.w);
      *(ushort4*)&znt[row][nl * 4] = o;
    }
  }
  __syncthreads();

  // ---- phase 2a: types 0 and 1 (a, b) — swapped-operand MFMA
  const u16* wgps[2] = {wb, wb + 32768};
  const u16* wpps[2] = {wb + 16384, wb + 49152};
  const float* bgps[2] = {agb, bgb};
  const float* bpps[2] = {apb, bpb};
  u16* outs[2] = {a_out, b_out};

#pragma unroll
  for (int tp = 0; tp < 2; ++tp) {
    const u16* wgp = wgps[tp];
    const u16* wpp = wpps[tp];
    const float* bgp = bgps[tp];
    const float* bpp = bpps[tp];
    u16* outp = outs[tp];

    bf16x8 wgf[8], wpf[8];
#pragma unroll
    for (int kk = 0; kk < 8; ++kk) {
      wgf[kk] = *(const bf16x8*)(wgp + h * CD + kk * 16 + s * 8);
      wpf[kk] = *(const bf16x8*)(wpp + h * CD + kk * 16 + s * 8);
    }

#pragma unroll
    for (int msb = 0; msb < 2; ++msb) {
      int mt = m0 + msb * 64;
      f32x16 accg[2], accp[2];
#pragma unroll
      for (int i = 0; i < 16; ++i) { accg[0][i] = 0; accg[1][i] = 0; accp[0][i] = 0; accp[1][i] = 0; }
#pragma unroll
      for (int kk = 0; kk < 8; ++kk) {
        bf16x8 zf0 = *(const bf16x8*)&znt[msb * 64 + nl][kk * 16 + s * 8];
        bf16x8 zf1 = *(const bf16x8*)&znt[msb * 64 + 32 + nl][kk * 16 + s * 8];
        accg[0] = __builtin_amdgcn_mfma_f32_32x32x16_bf16(wgf[kk], zf0, accg[0], 0, 0, 0);
        accg[1] = __builtin_amdgcn_mfma_f32_32x32x16_bf16(wgf[kk], zf1, accg[1], 0, 0, 0);
        accp[0] = __builtin_amdgcn_mfma_f32_32x32x16_bf16(wpf[kk], zf0, accp[0], 0, 0, 0);
        accp[1] = __builtin_amdgcn_mfma_f32_32x32x16_bf16(wpf[kk], zf1, accp[1], 0, 0, 0);
      }
      float mk0 = mask[mt + nl];
      float mk1 = mask[mt + 32 + nl];
#pragma unroll
      for (int r = 0; r < 16; ++r) {
        int hh = wvu * 32 + (r & 3) + 8 * (r >> 2) + 4 * s;
        float bg = bgp[hh], bp = bpp[hh];
        u16* rowp = outp + (size_t)hh * MTOT + mt + nl;
        rowp[0]  = f2bf(mk0 * sigmoidf(accg[0][r] + bg) * (accp[0][r] + bp));
        rowp[32] = f2bf(mk1 * sigmoidf(accg[1][r] + bg) * (accp[1][r] + bp));
      }
    }
  }

  // ---- phase 2b: type 2 (gate) — natural order
  {
    const u16* wgp = wb + 65536;
    bf16x8 wgf[8];
#pragma unroll
    for (int kk = 0; kk < 8; ++kk)
      wgf[kk] = *(const bf16x8*)(wgp + h * CD + kk * 16 + s * 8);
    float bgv = gb[h];
#pragma unroll
    for (int msb = 0; msb < 2; ++msb) {
      int mt = m0 + msb * 64;
      f32x16 accg[2];
#pragma unroll
      for (int i = 0; i < 16; ++i) { accg[0][i] = 0; accg[1][i] = 0; }
#pragma unroll
      for (int kk = 0; kk < 8; ++kk) {
        bf16x8 zf0 = *(const bf16x8*)&znt[msb * 64 + nl][kk * 16 + s * 8];
        bf16x8 zf1 = *(const bf16x8*)&znt[msb * 64 + 32 + nl][kk * 16 + s * 8];
        accg[0] = __builtin_amdgcn_mfma_f32_32x32x16_bf16(zf0, wgf[kk], accg[0], 0, 0, 0);
        accg[1] = __builtin_amdgcn_mfma_f32_32x32x16_bf16(zf1, wgf[kk], accg[1], 0, 0, 0);
      }
#pragma unroll
      for (int q = 0; q < 2; ++q)
#pragma unroll
        for (int r = 0; r < 16; ++r) {
          int rowoff = (r & 3) + 8 * (r >> 2) + 4 * s;
          int mg = mt + q * 32 + rowoff;
          gate_out[(size_t)mg * CD + h] = f2bf(sigmoidf(accg[q][r] + bgv));
        }
    }
  }
}

// ---------------------------------------------------------------------------
// K3: triangle einsum. Per channel h: X_h = A_h * B_h^T (bf16 NT).
// 128x128 tile, BK=64, DOUBLE-BUFFERED global_load_lds staging, XOR-swizzled.
// ---------------------------------------------------------------------------
__global__ __launch_bounds__(256) void k_tri(const u16* __restrict__ a,
                                             const u16* __restrict__ b,
                                             u16* __restrict__ x) {
  int h  = blockIdx.y;
  int tm = blockIdx.x / 3, tn = blockIdx.x % 3;
  int i0 = tm * 128, j0 = tn * 128;
  const u16* ah = a + (size_t)h * MTOT;
  const u16* bh = b + (size_t)h * MTOT;

  __shared__ u16 At[2][128][64];   // 16 KB each buffer, swizzled
  __shared__ u16 Bt[2][128][64];

  int lane = threadIdx.x & 63;
  int wvu = __builtin_amdgcn_readfirstlane(threadIdx.x >> 6);
  int nl = lane & 31, s = lane >> 5;
  int wr = wvu >> 1, wc = wvu & 1;
  int rl = lane >> 3, p8 = lane & 7;

  f32x16 acc[4];
#pragma unroll
  for (int q = 0; q < 4; ++q)
#pragma unroll
    for (int i = 0; i < 16; ++i) acc[q][i] = 0;

#define STAGE_TRI(bf, k0)                                                     \
  {                                                                           \
    _Pragma("unroll")                                                         \
    for (int j = 0; j < 4; ++j) {                                             \
      int row = wvu * 32 + j * 8 + rl;                                        \
      int gc = (p8 ^ (rl & 7)) << 3;                                          \
      gl16(ah + (size_t)(i0 + row) * NRES + (k0) + gc, &At[bf][wvu * 32 + j * 8][0]); \
      gl16(bh + (size_t)(j0 + row) * NRES + (k0) + gc, &Bt[bf][wvu * 32 + j * 8][0]); \
    }                                                                         \
  }

  STAGE_TRI(0, 0);
  __syncthreads();

  for (int kb = 0; kb < 6; ++kb) {
    int cur = kb & 1;
    if (kb < 5) STAGE_TRI(cur ^ 1, (kb + 1) * 64);
#pragma unroll
    for (int kk = 0; kk < 4; ++kk) {
      int c = ((kk * 2 + s) ^ (nl & 7)) << 3;
      bf16x8 af0 = *(const bf16x8*)&At[cur][wr * 64 + nl][c];
      bf16x8 af1 = *(const bf16x8*)&At[cur][wr * 64 + 32 + nl][c];
      bf16x8 bf0 = *(const bf16x8*)&Bt[cur][wc * 64 + nl][c];
      bf16x8 bf1 = *(const bf16x8*)&Bt[cur][wc * 64 + 32 + nl][c];
      acc[0] = __builtin_amdgcn_mfma_f32_32x32x16_bf16(af0, bf0, acc[0], 0, 0, 0);
      acc[1] = __builtin_amdgcn_mfma_f32_32x32x16_bf16(af0, bf1, acc[1], 0, 0, 0);
      acc[2] = __builtin_amdgcn_mfma_f32_32x32x16_bf16(af1, bf0, acc[2], 0, 0, 0);
      acc[3] = __builtin_amdgcn_mfma_f32_32x32x16_bf16(af1, bf1, acc[3], 0, 0, 0);
    }
    __syncthreads();
  }
#undef STAGE_TRI

  u16* xh = x + (size_t)h * MTOT;
#pragma unroll
  for (int msub = 0; msub < 2; ++msub)
#pragma unroll
    for (int nsub = 0; nsub < 2; ++nsub) {
      int j = j0 + wc * 64 + nsub * 32 + nl;
#pragma unroll
      for (int r = 0; r < 16; ++r) {
        int i = i0 + wr * 64 + msub * 32 + (r & 3) + 8 * (r >> 2) + 4 * s;
        xh[(size_t)i * NRES + j] = f2bf(acc[msub * 2 + nsub][r]);
      }
    }
}

// ---------------------------------------------------------------------------
// K4: out[m][o] = gate[m][o] * ( LN(x)[m][:] . z_w[o][:] + z_b[o] )
// ---------------------------------------------------------------------------
__global__ __launch_bounds__(256) void k_out(
    const u16* __restrict__ x, const u16* __restrict__ gate,
    const u16* __restrict__ wb,
    const float* __restrict__ lnw, const float* __restrict__ lnb,
    const float* __restrict__ zb, float* __restrict__ out) {
  int m0 = blockIdx.x * 64;
  int t = threadIdx.x;
  int wv = t >> 6, lane = t & 63, nl = lane & 31, s = lane >> 5;
  int o = wv * 32 + nl;

  __shared__ u16 xnt[64][136];

  const u16* zwp = wb + 5 * 16384;
  bf16x8 zwf[8];
#pragma unroll
  for (int kk = 0; kk < 8; ++kk)
    zwf[kk] = *(const bf16x8*)(zwp + o * CD + kk * 16 + s * 8);

#pragma unroll
  for (int ps = 0; ps < 2; ++ps) {
    int idx = ps * 256 + t;
    int hp = idx >> 3, mc = idx & 7;
    uint4 v0 = *(const uint4*)(x + (size_t)(2 * hp)     * MTOT + m0 + mc * 8);
    uint4 v1 = *(const uint4*)(x + (size_t)(2 * hp + 1) * MTOT + m0 + mc * 8);
    unsigned c0[4] = {v0.x, v0.y, v0.z, v0.w};
    unsigned c1[4] = {v1.x, v1.y, v1.z, v1.w};
#pragma unroll
    for (int q = 0; q < 4; ++q) {
      ushort2 lo, hi;
      lo.x = (u16)(c0[q] & 0xffffu); lo.y = (u16)(c1[q] & 0xffffu);
      hi.x = (u16)(c0[q] >> 16);     hi.y = (u16)(c1[q] >> 16);
      *(ushort2*)&xnt[mc * 8 + 2 * q][2 * hp]     = lo;
      *(ushort2*)&xnt[mc * 8 + 2 * q + 1][2 * hp] = hi;
    }
  }
  __syncthreads();

  int r = t >> 2, q = t & 3;
  float vals[32];
  float sum = 0;
#pragma unroll
  for (int j = 0; j < 32; ++j) { float v = bf2f(xnt[r][q * 32 + j]); vals[j] = v; sum += v; }
  sum += __shfl_xor(sum, 1);
  sum += __shfl_xor(sum, 2);
  float mu = sum * (1.0f / CD);
  float var = 0;
#pragma unroll
  for (int j = 0; j < 32; ++j) { float d = vals[j] - mu; var += d * d; }
  var += __shfl_xor(var, 1);
  var += __shfl_xor(var, 2);
  float rs = rsqrtf(var * (1.0f / CD) + 1e-5f);
#pragma unroll
  for (int j = 0; j < 32; ++j) {
    int hh = q * 32 + j;
    xnt[r][hh] = f2bf((vals[j] - mu) * rs * lnw[hh] + lnb[hh]);
  }
  __syncthreads();

  f32x16 acc[2];
#pragma unroll
  for (int i = 0; i < 16; ++i) { acc[0][i] = 0; acc[1][i] = 0; }
#pragma unroll
  for (int kk = 0; kk < 8; ++kk) {
    bf16x8 af0 = *(const bf16x8*)&xnt[nl][kk * 16 + s * 8];
    bf16x8 af1 = *(const bf16x8*)&xnt[32 + nl][kk * 16 + s * 8];
    acc[0] = __builtin_amdgcn_mfma_f32_32x32x16_bf16(af0, zwf[kk], acc[0], 0, 0, 0);
    acc[1] = __builtin_amdgcn_mfma_f32_32x32x16_bf16(af1, zwf[kk], acc[1], 0, 0, 0);
  }

  float zbv = zb[o];
#pragma unroll
  for (int ms = 0; ms < 2; ++ms)
#pragma unroll
    for (int rr = 0; rr < 16; ++rr) {
      int rowoff = (rr & 3) + 8 * (rr >> 2) + 4 * s;
      int mg = m0 + ms * 32 + rowoff;
      float g = bf2f(gate[(size_t)mg * CD + o]);
      out[(size_t)mg * CD + o] = g * (acc[ms][rr] + zbv);
    }
}

// ---------------------------------------------------------------------------
extern "C" void kernel_launch(void* const* d_in, const int* in_sizes, int n_in,
                              void* d_out, int out_size, void* d_ws, size_t ws_size,
                              hipStream_t stream) {
  const float* z       = (const float*)d_in[0];
  const float* mask    = (const float*)d_in[1];
  const float* ln_in_w = (const float*)d_in[2];
  const float* ln_in_b = (const float*)d_in[3];
  const float* a_g_w   = (const float*)d_in[4];
  const float* a_g_b   = (const float*)d_in[5];
  const float* a_p_w   = (const float*)d_in[6];
  const float* a_p_b   = (const float*)d_in[7];
  const float* b_g_w   = (const float*)d_in[8];
  const float* b_g_b   = (const float*)d_in[9];
  const float* b_p_w   = (const float*)d_in[10];
  const float* b_p_b   = (const float*)d_in[11];
  const float* g_w     = (const float*)d_in[12];
  const float* g_b     = (const float*)d_in[13];
  const float* ln_o_w  = (const float*)d_in[14];
  const float* ln_o_b  = (const float*)d_in[15];
  const float* z_w     = (const float*)d_in[16];
  const float* z_b     = (const float*)d_in[17];
  float* out = (float*)d_out;

  const size_t SZ = (size_t)MTOT * CD * sizeof(u16);
  char* w = (char*)d_ws;
  u16* x    = (u16*)(w);            // k_tri output
  u16* a    = (u16*)(w + SZ);
  u16* b    = (u16*)(w + 2 * SZ);
  u16* gate = (u16*)(w + 3 * SZ);
  u16* wb   = (u16*)(w + 4 * SZ);
  (void)ws_size; (void)in_sizes; (void)n_in; (void)out_size;

  k_cvt_w<<<384, 256, 0, stream>>>(a_g_w, a_p_w, b_g_w, b_p_w, g_w, z_w, wb);
  k_fused<<<MTOT / 128, 256, 0, stream>>>(z, mask, ln_in_w, ln_in_b, wb,
      a_g_b, a_p_b, b_g_b, b_p_b, g_b, a, b, gate);
  k_tri<<<dim3(9, 128), 256, 0, stream>>>(a, b, x);
  k_out<<<MTOT / 64, 256, 0, stream>>>(x, gate, wb, ln_o_w, ln_o_b, z_b, out);
}

// Round 5
// 297.765 us; speedup vs baseline: 1.0870x; 1.0870x over previous
//
#include <hip/hip_runtime.h>

#define NRES 384
#define CD   128
#define MTOT (NRES*NRES)   /* 147456 */

typedef unsigned short u16;
typedef __bf16 bf16x8 __attribute__((ext_vector_type(8)));
typedef float  f32x16 __attribute__((ext_vector_type(16)));

static __device__ __forceinline__ u16 f2bf(float f) {
  __bf16 b = (__bf16)f;
  return __builtin_bit_cast(u16, b);
}
static __device__ __forceinline__ float bf2f(u16 v) {
  return __uint_as_float(((unsigned)v) << 16);
}
static __device__ __forceinline__ float sigmoidf(float x) {
  return 1.0f / (1.0f + __expf(-x));
}

// async global->LDS, 16B per lane; LDS dest = wave-uniform base + lane*16
static __device__ __forceinline__ void gl16(const void* g, void* l) {
  __builtin_amdgcn_global_load_lds(
      (const __attribute__((address_space(1))) void*)g,
      (__attribute__((address_space(3))) void*)l, 16, 0, 0);
}

// ---------------------------------------------------------------------------
// K0: convert the six 128x128 fp32 weight matrices to bf16 (row-major [n][k])
// order in wb: a_g_w, a_p_w, b_g_w, b_p_w, g_w, z_w
// ---------------------------------------------------------------------------
__global__ void k_cvt_w(const float* w0, const float* w1, const float* w2,
                        const float* w3, const float* w4, const float* w5,
                        u16* wb) {
  int i = blockIdx.x * 256 + threadIdx.x;
  const float* srcs[6] = {w0, w1, w2, w3, w4, w5};
  wb[i] = f2bf(srcs[i >> 14][i & 16383]);
}

// ---------------------------------------------------------------------------
// K1: LayerNorm(z) -> zn bf16 [m][c]
// ---------------------------------------------------------------------------
__global__ __launch_bounds__(256) void k_ln_in(const float* __restrict__ z,
                                               const float* __restrict__ w,
                                               const float* __restrict__ b,
                                               u16* __restrict__ zn) {
  int wv = threadIdx.x >> 6, lane = threadIdx.x & 63;
  float2 wv2 = ((const float2*)w)[lane];
  float2 bv2 = ((const float2*)b)[lane];
  for (int rr = 0; rr < 4; ++rr) {
    size_t row = (size_t)blockIdx.x * 16 + wv * 4 + rr;
    float2 v = ((const float2*)(z + row * CD))[lane];
    float s = v.x + v.y;
#pragma unroll
    for (int off = 32; off >= 1; off >>= 1) s += __shfl_xor(s, off);
    float mu = s * (1.0f / CD);
    float dx = v.x - mu, dy = v.y - mu;
    float vr = dx * dx + dy * dy;
#pragma unroll
    for (int off = 32; off >= 1; off >>= 1) vr += __shfl_xor(vr, off);
    float rs = rsqrtf(vr * (1.0f / CD) + 1e-5f);
    ushort2 o;
    o.x = f2bf(dx * rs * wv2.x + bv2.x);
    o.y = f2bf(dy * rs * wv2.y + bv2.y);
    ((ushort2*)(zn + row * CD))[lane] = o;
  }
}

// ---------------------------------------------------------------------------
// K2: a/b projections off zn (gate GEMM moved to k_out).
// M-tile 256/block, 4x64 subtiles, double-buffered global_load_lds staging,
// XOR-swizzled. Swapped-operand MFMA -> C[h][m], coalesced [h][m] stores.
// ---------------------------------------------------------------------------
__global__ __launch_bounds__(256) void k_proj(
    const u16* __restrict__ zn, const float* __restrict__ mask,
    const u16* __restrict__ wb,
    const float* __restrict__ agb, const float* __restrict__ apb,
    const float* __restrict__ bgb, const float* __restrict__ bpb,
    u16* __restrict__ a_out, u16* __restrict__ b_out) {
  int type = blockIdx.y;
  int m_base = blockIdx.x * 256;
  int lane = threadIdx.x & 63;
  int wvu = __builtin_amdgcn_readfirstlane(threadIdx.x >> 6);
  int nl = lane & 31, s = lane >> 5;
  int h = wvu * 32 + nl;

  const u16* wgp = (type == 0) ? wb : wb + 32768;
  const u16* wpp = (type == 0) ? wb + 16384 : wb + 49152;
  const float* bgp = (type == 0) ? agb : bgb;
  const float* bpp = (type == 0) ? apb : bpb;
  u16* outp = (type == 0) ? a_out : b_out;

  __shared__ u16 znt[2][64][128];   // 32 KB, swizzled layout

  // register-cache weight fragments (reused across 4 subtiles)
  bf16x8 wgf[8], wpf[8];
#pragma unroll
  for (int kk = 0; kk < 8; ++kk) {
    wgf[kk] = *(const bf16x8*)(wgp + h * CD + kk * 16 + s * 8);
    wpf[kk] = *(const bf16x8*)(wpp + h * CD + kk * 16 + s * 8);
  }

  int rl = lane >> 4, p16 = lane & 15;
#define STAGE_ZNT(mt, bf)                                                   \
  {                                                                         \
    _Pragma("unroll")                                                       \
    for (int j = 0; j < 4; ++j) {                                           \
      int row = wvu * 16 + j * 4 + rl;                                      \
      int gc = (p16 ^ (row & 7)) << 3;                                      \
      gl16(zn + (size_t)((mt) + row) * CD + gc, &znt[bf][wvu * 16 + j * 4][0]); \
    }                                                                       \
  }

  STAGE_ZNT(m_base, 0);
  __syncthreads();

  for (int ms = 0; ms < 4; ++ms) {
    int cur = ms & 1;
    if (ms < 3) STAGE_ZNT(m_base + (ms + 1) * 64, cur ^ 1);
    int mt = m_base + ms * 64;

    f32x16 accg[2], accp[2];
#pragma unroll
    for (int i = 0; i < 16; ++i) { accg[0][i] = 0; accg[1][i] = 0; accp[0][i] = 0; accp[1][i] = 0; }
#pragma unroll
    for (int kk = 0; kk < 8; ++kk) {
      int c = ((kk * 2 + s) ^ (nl & 7)) << 3;
      bf16x8 zf0 = *(const bf16x8*)&znt[cur][nl][c];
      bf16x8 zf1 = *(const bf16x8*)&znt[cur][32 + nl][c];
      accg[0] = __builtin_amdgcn_mfma_f32_32x32x16_bf16(wgf[kk], zf0, accg[0], 0, 0, 0);
      accg[1] = __builtin_amdgcn_mfma_f32_32x32x16_bf16(wgf[kk], zf1, accg[1], 0, 0, 0);
      accp[0] = __builtin_amdgcn_mfma_f32_32x32x16_bf16(wpf[kk], zf0, accp[0], 0, 0, 0);
      accp[1] = __builtin_amdgcn_mfma_f32_32x32x16_bf16(wpf[kk], zf1, accp[1], 0, 0, 0);
    }
    __syncthreads();
    float mk0 = mask[mt + nl];
    float mk1 = mask[mt + 32 + nl];
#pragma unroll
    for (int r = 0; r < 16; ++r) {
      int hh = wvu * 32 + (r & 3) + 8 * (r >> 2) + 4 * s;
      float bg = bgp[hh], bp = bpp[hh];
      u16* rowp = outp + (size_t)hh * MTOT + mt + nl;
      rowp[0]  = f2bf(mk0 * sigmoidf(accg[0][r] + bg) * (accp[0][r] + bp));
      rowp[32] = f2bf(mk1 * sigmoidf(accg[1][r] + bg) * (accp[1][r] + bp));
    }
  }
#undef STAGE_ZNT
}

// ---------------------------------------------------------------------------
// K3: triangle einsum. Per channel h: X_h = A_h * B_h^T (bf16 NT).
// 128x128 tile, BK=64, double-buffered global_load_lds staging, XOR-swizzled.
// ---------------------------------------------------------------------------
__global__ __launch_bounds__(256) void k_tri(const u16* __restrict__ a,
                                             const u16* __restrict__ b,
                                             u16* __restrict__ x) {
  int h  = blockIdx.y;
  int tm = blockIdx.x / 3, tn = blockIdx.x % 3;
  int i0 = tm * 128, j0 = tn * 128;
  const u16* ah = a + (size_t)h * MTOT;
  const u16* bh = b + (size_t)h * MTOT;

  __shared__ u16 At[2][128][64];
  __shared__ u16 Bt[2][128][64];

  int lane = threadIdx.x & 63;
  int wvu = __builtin_amdgcn_readfirstlane(threadIdx.x >> 6);
  int nl = lane & 31, s = lane >> 5;
  int wr = wvu >> 1, wc = wvu & 1;
  int rl = lane >> 3, p8 = lane & 7;

  f32x16 acc[4];
#pragma unroll
  for (int q = 0; q < 4; ++q)
#pragma unroll
    for (int i = 0; i < 16; ++i) acc[q][i] = 0;

#define STAGE_TRI(bf, k0)                                                     \
  {                                                                           \
    _Pragma("unroll")                                                         \
    for (int j = 0; j < 4; ++j) {                                             \
      int row = wvu * 32 + j * 8 + rl;                                        \
      int gc = (p8 ^ (rl & 7)) << 3;                                          \
      gl16(ah + (size_t)(i0 + row) * NRES + (k0) + gc, &At[bf][wvu * 32 + j * 8][0]); \
      gl16(bh + (size_t)(j0 + row) * NRES + (k0) + gc, &Bt[bf][wvu * 32 + j * 8][0]); \
    }                                                                         \
  }

  STAGE_TRI(0, 0);
  __syncthreads();

  for (int kb = 0; kb < 6; ++kb) {
    int cur = kb & 1;
    if (kb < 5) STAGE_TRI(cur ^ 1, (kb + 1) * 64);
#pragma unroll
    for (int kk = 0; kk < 4; ++kk) {
      int c = ((kk * 2 + s) ^ (nl & 7)) << 3;
      bf16x8 af0 = *(const bf16x8*)&At[cur][wr * 64 + nl][c];
      bf16x8 af1 = *(const bf16x8*)&At[cur][wr * 64 + 32 + nl][c];
      bf16x8 bf0 = *(const bf16x8*)&Bt[cur][wc * 64 + nl][c];
      bf16x8 bf1 = *(const bf16x8*)&Bt[cur][wc * 64 + 32 + nl][c];
      acc[0] = __builtin_amdgcn_mfma_f32_32x32x16_bf16(af0, bf0, acc[0], 0, 0, 0);
      acc[1] = __builtin_amdgcn_mfma_f32_32x32x16_bf16(af0, bf1, acc[1], 0, 0, 0);
      acc[2] = __builtin_amdgcn_mfma_f32_32x32x16_bf16(af1, bf0, acc[2], 0, 0, 0);
      acc[3] = __builtin_amdgcn_mfma_f32_32x32x16_bf16(af1, bf1, acc[3], 0, 0, 0);
    }
    __syncthreads();
  }
#undef STAGE_TRI

  u16* xh = x + (size_t)h * MTOT;
#pragma unroll
  for (int msub = 0; msub < 2; ++msub)
#pragma unroll
    for (int nsub = 0; nsub < 2; ++nsub) {
      int j = j0 + wc * 64 + nsub * 32 + nl;
#pragma unroll
      for (int r = 0; r < 16; ++r) {
        int i = i0 + wr * 64 + msub * 32 + (r & 3) + 8 * (r >> 2) + 4 * s;
        xh[(size_t)i * NRES + j] = f2bf(acc[msub * 2 + nsub][r]);
      }
    }
}

// ---------------------------------------------------------------------------
// K4: out[m][o] = sigmoid(zn.g_w^T + g_b)[m][o] * ( LN(x)[m][:].z_w[o][:] + z_b[o] )
// phase A: stage zn tile (natural [m][c]), gate GEMM -> fp32 regs
// phase B: reuse LDS buffer for x transpose, per-row LN, z_w GEMM, epilogue
// ---------------------------------------------------------------------------
__global__ __launch_bounds__(256) void k_out(
    const u16* __restrict__ x, const u16* __restrict__ zn,
    const u16* __restrict__ wb, const float* __restrict__ gb,
    const float* __restrict__ lnw, const float* __restrict__ lnb,
    const float* __restrict__ zb, float* __restrict__ out) {
  int m0 = blockIdx.x * 64;
  int t = threadIdx.x;
  int wv = t >> 6, lane = t & 63, nl = lane & 31, s = lane >> 5;
  int o = wv * 32 + nl;

  __shared__ u16 tile[64][136];

  const u16* gwp = wb + 4 * 16384;   // g_w
  const u16* zwp = wb + 5 * 16384;   // z_w

  // ---- phase A: gate GEMM (natural order, C[m][o])
  bf16x8 gwf[8];
#pragma unroll
  for (int kk = 0; kk < 8; ++kk)
    gwf[kk] = *(const bf16x8*)(gwp + o * CD + kk * 16 + s * 8);

#pragma unroll
  for (int it = 0; it < 4; ++it) {
    int idx = it * 256 + t;          // 1024 chunks of 8 bf16
    int r = idx >> 4, c8 = idx & 15;
    *(uint4*)&tile[r][c8 * 8] =
        *(const uint4*)(zn + (size_t)(m0 + r) * CD + c8 * 8);
  }
  __syncthreads();

  f32x16 gacc[2];
#pragma unroll
  for (int i = 0; i < 16; ++i) { gacc[0][i] = 0; gacc[1][i] = 0; }
#pragma unroll
  for (int kk = 0; kk < 8; ++kk) {
    bf16x8 zf0 = *(const bf16x8*)&tile[nl][kk * 16 + s * 8];
    bf16x8 zf1 = *(const bf16x8*)&tile[32 + nl][kk * 16 + s * 8];
    gacc[0] = __builtin_amdgcn_mfma_f32_32x32x16_bf16(zf0, gwf[kk], gacc[0], 0, 0, 0);
    gacc[1] = __builtin_amdgcn_mfma_f32_32x32x16_bf16(zf1, gwf[kk], gacc[1], 0, 0, 0);
  }
  float gbv = gb[o];
  float gv[32];
#pragma unroll
  for (int ms = 0; ms < 2; ++ms)
#pragma unroll
    for (int r = 0; r < 16; ++r)
      gv[ms * 16 + r] = sigmoidf(gacc[ms][r] + gbv);
  __syncthreads();   // tile reads done; safe to overwrite

  // ---- phase B: transpose x[h][m] -> tile[m][h]
  bf16x8 zwf[8];
#pragma unroll
  for (int kk = 0; kk < 8; ++kk)
    zwf[kk] = *(const bf16x8*)(zwp + o * CD + kk * 16 + s * 8);

#pragma unroll
  for (int ps = 0; ps < 2; ++ps) {
    int idx = ps * 256 + t;
    int hp = idx >> 3, mc = idx & 7;
    uint4 v0 = *(const uint4*)(x + (size_t)(2 * hp)     * MTOT + m0 + mc * 8);
    uint4 v1 = *(const uint4*)(x + (size_t)(2 * hp + 1) * MTOT + m0 + mc * 8);
    unsigned c0[4] = {v0.x, v0.y, v0.z, v0.w};
    unsigned c1[4] = {v1.x, v1.y, v1.z, v1.w};
#pragma unroll
    for (int q = 0; q < 4; ++q) {
      ushort2 lo, hi;
      lo.x = (u16)(c0[q] & 0xffffu); lo.y = (u16)(c1[q] & 0xffffu);
      hi.x = (u16)(c0[q] >> 16);     hi.y = (u16)(c1[q] >> 16);
      *(ushort2*)&tile[mc * 8 + 2 * q][2 * hp]     = lo;
      *(ushort2*)&tile[mc * 8 + 2 * q + 1][2 * hp] = hi;
    }
  }
  __syncthreads();

  // LayerNorm per m-row
  int r = t >> 2, q = t & 3;
  float vals[32];
  float sum = 0;
#pragma unroll
  for (int j = 0; j < 32; ++j) { float v = bf2f(tile[r][q * 32 + j]); vals[j] = v; sum += v; }
  sum += __shfl_xor(sum, 1);
  sum += __shfl_xor(sum, 2);
  float mu = sum * (1.0f / CD);
  float var = 0;
#pragma unroll
  for (int j = 0; j < 32; ++j) { float d = vals[j] - mu; var += d * d; }
  var += __shfl_xor(var, 1);
  var += __shfl_xor(var, 2);
  float rs = rsqrtf(var * (1.0f / CD) + 1e-5f);
#pragma unroll
  for (int j = 0; j < 32; ++j) {
    int hh = q * 32 + j;
    tile[r][hh] = f2bf((vals[j] - mu) * rs * lnw[hh] + lnb[hh]);
  }
  __syncthreads();

  f32x16 acc[2];
#pragma unroll
  for (int i = 0; i < 16; ++i) { acc[0][i] = 0; acc[1][i] = 0; }
#pragma unroll
  for (int kk = 0; kk < 8; ++kk) {
    bf16x8 af0 = *(const bf16x8*)&tile[nl][kk * 16 + s * 8];
    bf16x8 af1 = *(const bf16x8*)&tile[32 + nl][kk * 16 + s * 8];
    acc[0] = __builtin_amdgcn_mfma_f32_32x32x16_bf16(af0, zwf[kk], acc[0], 0, 0, 0);
    acc[1] = __builtin_amdgcn_mfma_f32_32x32x16_bf16(af1, zwf[kk], acc[1], 0, 0, 0);
  }

  float zbv = zb[o];
#pragma unroll
  for (int ms = 0; ms < 2; ++ms)
#pragma unroll
    for (int rr = 0; rr < 16; ++rr) {
      int rowoff = (rr & 3) + 8 * (rr >> 2) + 4 * s;
      int mg = m0 + ms * 32 + rowoff;
      out[(size_t)mg * CD + o] = gv[ms * 16 + rr] * (acc[ms][rr] + zbv);
    }
}

// ---------------------------------------------------------------------------
extern "C" void kernel_launch(void* const* d_in, const int* in_sizes, int n_in,
                              void* d_out, int out_size, void* d_ws, size_t ws_size,
                              hipStream_t stream) {
  const float* z       = (const float*)d_in[0];
  const float* mask    = (const float*)d_in[1];
  const float* ln_in_w = (const float*)d_in[2];
  const float* ln_in_b = (const float*)d_in[3];
  const float* a_g_w   = (const float*)d_in[4];
  const float* a_g_b   = (const float*)d_in[5];
  const float* a_p_w   = (const float*)d_in[6];
  const float* a_p_b   = (const float*)d_in[7];
  const float* b_g_w   = (const float*)d_in[8];
  const float* b_g_b   = (const float*)d_in[9];
  const float* b_p_w   = (const float*)d_in[10];
  const float* b_p_b   = (const float*)d_in[11];
  const float* g_w     = (const float*)d_in[12];
  const float* g_b     = (const float*)d_in[13];
  const float* ln_o_w  = (const float*)d_in[14];
  const float* ln_o_b  = (const float*)d_in[15];
  const float* z_w     = (const float*)d_in[16];
  const float* z_b     = (const float*)d_in[17];
  float* out = (float*)d_out;

  const size_t SZ = (size_t)MTOT * CD * sizeof(u16);
  char* w = (char*)d_ws;
  u16* zn = (u16*)(w);              // live until k_out
  u16* a  = (u16*)(w + SZ);
  u16* b  = (u16*)(w + 2 * SZ);
  u16* x  = (u16*)(w + 3 * SZ);
  u16* wb = (u16*)(w + 4 * SZ);
  (void)ws_size; (void)in_sizes; (void)n_in; (void)out_size;

  k_cvt_w<<<384, 256, 0, stream>>>(a_g_w, a_p_w, b_g_w, b_p_w, g_w, z_w, wb);
  k_ln_in<<<MTOT / 16, 256, 0, stream>>>(z, ln_in_w, ln_in_b, zn);
  k_proj<<<dim3(MTOT / 256, 2), 256, 0, stream>>>(zn, mask, wb,
      a_g_b, a_p_b, b_g_b, b_p_b, a, b);
  k_tri<<<dim3(9, 128), 256, 0, stream>>>(a, b, x);
  k_out<<<MTOT / 64, 256, 0, stream>>>(x, zn, wb, g_b, ln_o_w, ln_o_b, z_b, out);
}